// Round 1
// baseline (349.105 us; speedup 1.0000x reference)
//
#include <hip/hip_runtime.h>
#include <math.h>

// glp_rotation_pool: rotate (B,C,H,W,A) slices by -(360/A)*(a%K) degrees
// (nearest-neighbor, zero fill) then max-pool groups of K along A.
// Shapes hardcoded per setup_inputs(): B=8,C=16,H=128,W=128,A=24,K=4 -> G=6.
//
// R4 redesign vs R3 (306us, ~190 cyc/mem-instr => TA/scatter-bound):
//  - The rotation gather is a scatter; doing it against global memory 4x per
//    output serializes the vector-memory path. Instead: per (slice, 32x32
//    output tile, k) stage the <=47x47 source bbox's 6 needed channels
//    (a == k mod 4) into LDS with perfectly-coalesced float4 loads, then
//    gather data-dependently from LDS.
//  - Staging identity: within a bbox row the needed floats are every 4th
//    float starting at k, so lane q loads float4 #q of the row span and
//    keeps element k; its LDS slot is exactly q (record q/6, g q%6).
//    1KB/wave contiguous global reads, stride-1 LDS writes.
//  - 1024 thr/block (1 px/thread), LDS 48*48*6*4 = 54KB -> 2 blocks/CU;
//    one block stages while the other gathers.
//  - XCD swizzle: each XCD owns 16 slices (1.57MB each, L2-resident).

// Replicate reference f32 arithmetic exactly: no FMA contraction in this TU.
#pragma clang fp contract(off)

#define BB 8
#define CC 16
#define HH 128
#define WW 128
#define AA 24
#define KK 4
#define GG 6    // AA / KK
#define TS 32   // output tile side
#define BBX 48  // LDS bbox allocation side (worst real bbox <= 46)
#define LROW (BBX * GG)  // 288 floats per staged bbox row

__global__ __launch_bounds__(1024, 8) void glp_rotation_pool_kernel(
    const float* __restrict__ img, float* __restrict__ out) {
  __shared__ float lds[BBX * LROW];  // 55296 B

  // 2048 blocks = 128 slices x 16 tiles; xcd = blk & 7 round-robin heuristic
  // so each XCD works 16 slices, tiles of one slice together in its L2.
  int blk = blockIdx.x;
  int xcd = blk & 7;
  int i = blk >> 3;                // 0..255
  int bc = (xcd << 4) | (i >> 4);  // slice 0..127
  int tile = i & 15;
  int ty = (tile >> 2) << 5;  // 0,32,64,96
  int tx = (tile & 3) << 5;

  int tid = threadIdx.x;  // 0..1023
  int py = tid >> 5;      // 0..31
  int px = tid & 31;      // 0..31
  int wave = tid >> 6;    // 0..15
  int lane = tid & 63;    // 0..63

  const float cx = 63.5f;  // (W-1)/2
  const float cy = 63.5f;

  const float* base = img + (size_t)bc * (HH * WW * AA);

  float xg = (float)(tx + px) - cx;
  float yg = (float)(ty + py) - cy;
  // tile corner offsets (for the per-k source bbox)
  float xga = (float)tx - cx, xgb = (float)(tx + TS - 1) - cx;
  float yga = (float)ty - cy, ygb = (float)(ty + TS - 1) - cy;

  float res0 = -INFINITY, res1 = -INFINITY, res2 = -INFINITY;
  float res3 = -INFINITY, res4 = -INFINITY, res5 = -INFINITY;

#pragma unroll
  for (int k = 0; k < KK; ++k) {
    // theta = deg2rad(-15*k) in f32 exactly like the reference.
    float tdeg = -15.0f * (float)k;
    float theta = tdeg * 0.017453292519943295f;
    // Correctly-rounded f32 trig via double eval (constant-folds per k).
    float cth = (float)cos((double)theta);
    float sth = (float)sin((double)theta);

    // Source bbox from the 4 tile corners, with the SAME f32 expressions as
    // the per-pixel path below (f32 +/* are monotone => corner extremes
    // bound all interior pixels; rint(v) in [floor(v), ceil(v)]).
    float xs00 = cth * xga + sth * yga + cx;
    float xs01 = cth * xga + sth * ygb + cx;
    float xs10 = cth * xgb + sth * yga + cx;
    float xs11 = cth * xgb + sth * ygb + cx;
    float ys00 = (-sth) * xga + cth * yga + cy;
    float ys01 = (-sth) * xga + cth * ygb + cy;
    float ys10 = (-sth) * xgb + cth * yga + cy;
    float ys11 = (-sth) * xgb + cth * ygb + cy;
    float minxs = fminf(fminf(xs00, xs01), fminf(xs10, xs11));
    float maxxs = fmaxf(fmaxf(xs00, xs01), fmaxf(xs10, xs11));
    float minys = fminf(fminf(ys00, ys01), fminf(ys10, ys11));
    float maxys = fmaxf(fmaxf(ys00, ys01), fmaxf(ys10, ys11));
    int bx0 = max(0, (int)floorf(minxs));
    int bx1 = min(WW - 1, (int)ceilf(maxxs));
    int by0 = max(0, (int)floorf(minys));
    int by1 = min(HH - 1, (int)ceilf(maxys));
    int NC = min(bx1 - bx0 + 1, BBX);  // clamps are provably no-ops
    int NR = min(by1 - by0 + 1, BBX);

    __syncthreads();  // previous k's gather done before LDS overwrite
    if (NC > 0 && NR > 0) {
      int rowq = GG * NC;  // float4s per bbox row (each yields 1 float)
      for (int dy = wave; dy < NR; dy += 16) {
        // row base float index = ((by0+dy)*128 + bx0)*24: multiple of 4
        // (24 | base) => float4 #q covers floats 4q..4q+3 of the row span;
        // element k is channel (k + 4*(q%6)) of record bx0 + q/6,
        // and its LDS slot within the row is exactly q.
        const float4* rowp =
            (const float4*)(base + (size_t)((by0 + dy) * WW + bx0) * AA);
        float* lrow = &lds[dy * LROW];
        for (int q = lane; q < rowq; q += 64) {
          float4 v = rowp[q];
          float e = (k == 0) ? v.x : (k == 1) ? v.y : (k == 2) ? v.z : v.w;
          lrow[q] = e;
        }
      }
    }
    __syncthreads();

    // Per-pixel gather (g-independent source coordinate).
    float xs = cth * xg + sth * yg + cx;  // no fma (contract off)
    float ys = (-sth) * xg + cth * yg + cy;
    int xi = (int)rintf(xs);  // round-half-even == jnp.round
    int yi = (int)rintf(ys);
    bool valid = ((unsigned)xi < (unsigned)WW) & ((unsigned)yi < (unsigned)HH);
    int xc = min(max(xi, 0), WW - 1);
    int yc = min(max(yi, 0), HH - 1);
    // valid => (yc-by0, xc-bx0) lies inside the clipped bbox; clamp only to
    // keep LDS addressing in-bounds for masked-off (invalid) lanes.
    int dxr = min(max(xc - bx0, 0), BBX - 1);
    int dyr = min(max(yc - by0, 0), BBX - 1);
    const float2* lp = (const float2*)&lds[dyr * LROW + dxr * GG];  // 8B-aligned
    float2 v01 = lp[0];
    float2 v23 = lp[1];
    float2 v45 = lp[2];
    res0 = fmaxf(res0, valid ? v01.x : 0.0f);  // zero fill joins the max
    res1 = fmaxf(res1, valid ? v01.y : 0.0f);
    res2 = fmaxf(res2, valid ? v23.x : 0.0f);
    res3 = fmaxf(res3, valid ? v23.y : 0.0f);
    res4 = fmaxf(res4, valid ? v45.x : 0.0f);
    res5 = fmaxf(res5, valid ? v45.y : 0.0f);
  }

  // out float index = ((bc*H*W + (ty+py)*W + tx+px)*G + g); 24B per pixel,
  // 8B-aligned => 3x float2 stores.
  size_t opix =
      ((size_t)bc * (HH * WW) + (size_t)(ty + py) * WW + (tx + px)) * GG;
  float2* op = (float2*)&out[opix];
  op[0] = make_float2(res0, res1);
  op[1] = make_float2(res2, res3);
  op[2] = make_float2(res4, res5);
}

extern "C" void kernel_launch(void* const* d_in, const int* in_sizes, int n_in,
                              void* d_out, int out_size, void* d_ws,
                              size_t ws_size, hipStream_t stream) {
  const float* img = (const float*)d_in[0];
  float* out = (float*)d_out;
  // 128 slices * 16 tiles = 2048 blocks of 1024 threads
  dim3 grid(BB * CC * 16);
  dim3 block(1024);
  glp_rotation_pool_kernel<<<grid, block, 0, stream>>>(img, out);
}

// Round 2
// 330.714 us; speedup vs baseline: 1.0556x; 1.0556x over previous
//
#include <hip/hip_runtime.h>
#include <math.h>

// glp_rotation_pool: rotate (B,C,H,W,A) slices by -(360/A)*(a%K) degrees
// (nearest-neighbor, zero fill) then max-pool groups of K along A.
// Shapes hardcoded per setup_inputs(): B=8,C=16,H=128,W=128,A=24,K=4 -> G=6.
//
// R5 vs R4 (kernel 149us; stage->vmcnt(0)->barrier->gather chain was ~3x
// serial overhead over the ~50us of real pipe work):
//  - async global_load_lds (size=4) staging: per-lane global addr at stride
//    16B picks channel k of each float4; LDS dest is linear (uniform base +
//    lane*4). No VGPR round-trip, no ds_write, no select VALU.
//  - LDS double-buffer with per-k fixed window sizes (proven bounds):
//    k0 32x16, k1 35x24, k2 36x30, k3 34x34 -> buf0 6480 + buf1 6936 floats
//    = 53.7KB < 64KB static. buf0 serves k0,k2; buf1 serves k1,k3.
//  - counted s_waitcnt vmcnt(N) + raw s_barrier (8-phase-template pattern):
//    loads for k+1/k+2 stay in flight across each gather phase; never drain
//    to vmcnt(0) mid-loop.
//  - tile 32x16 (512 thr, 8 waves), 2 blocks/CU (107KB LDS) so two blocks'
//    phases offset each other.
//  - windows are always fully inside the image (origin clamped; window size
//    >= max bbox extent per k), so staging needs no per-lane clamping and
//    valid pixels provably land inside the staged window.

// Replicate reference f32 arithmetic exactly: no FMA contraction in this TU.
#pragma clang fp contract(off)

#define HH 128
#define WW 128
#define AA 24
#define GG 6
#define TW 32
#define TH 16

#define GLDS(gp, lp)                                       \
  __builtin_amdgcn_global_load_lds(                        \
      (const __attribute__((address_space(1))) void*)(gp), \
      (__attribute__((address_space(3))) void*)(lp), 4, 0, 0)

template <int K>
__device__ __forceinline__ void ktrig(float& cth, float& sth) {
  // theta = deg2rad(-15*K) in f32 exactly like the reference; correctly-
  // rounded f32 trig via double eval (constant-folds per K).
  float tdeg = -15.0f * (float)K;
  float theta = tdeg * 0.017453292519943295f;
  cth = (float)cos((double)theta);
  sth = (float)sin((double)theta);
}

// Window origin for k: rint(min corner xs/ys), clamped so the fixed WKxHK
// window lies fully inside the image. Monotone f32 ops => corner min bounds
// all interior pixels; WK/HK chosen so rint(max)-rint(min) <= WK-1 (width
// bound w+1 with w = 31c+15s etc., margins >= 0.17 px >> f32 eps).
template <int K, int WK, int HK>
__device__ __forceinline__ void window_k(float xga, float xgb, float yga,
                                         float ygb, int& bx0, int& by0) {
  float cth, sth;
  ktrig<K>(cth, sth);
  float xs00 = cth * xga + sth * yga + 63.5f;
  float xs01 = cth * xga + sth * ygb + 63.5f;
  float xs10 = cth * xgb + sth * yga + 63.5f;
  float xs11 = cth * xgb + sth * ygb + 63.5f;
  float ys00 = (-sth) * xga + cth * yga + 63.5f;
  float ys01 = (-sth) * xga + cth * ygb + 63.5f;
  float ys10 = (-sth) * xgb + cth * yga + 63.5f;
  float ys11 = (-sth) * xgb + cth * ygb + 63.5f;
  float minxs = fminf(fminf(xs00, xs01), fminf(xs10, xs11));
  float minys = fminf(fminf(ys00, ys01), fminf(ys10, ys11));
  bx0 = min(max((int)rintf(minxs), 0), WW - WK);
  by0 = min(max((int)rintf(minys), 0), HH - HK);
}

// Stage channel-K plane of the WKxHK window into LDS via async
// global_load_lds. Per row: LR = WK*6 floats; lane q<-global float 4q+K.
// Issue count per wave is compile-time uniform: NJ*(NFULL + (REM?1:0)).
template <int K, int WK, int HK>
__device__ __forceinline__ void stage_k(const float* sbase, float* lplane,
                                        int bx0, int by0, int wave, int lane) {
  constexpr int LR = WK * GG;
  constexpr int NFULL = LR >> 6;
  constexpr int REM = LR & 63;
  constexpr int NJ = (HK + 7) >> 3;
#pragma unroll
  for (int j = 0; j < NJ; ++j) {
    int dy = wave + 8 * j;
    dy = dy < HK ? dy : HK - 1;  // dup rows keep counts uniform (same data)
    const float* row = sbase + ((by0 + dy) * WW + bx0) * AA + K;
    float* lrow = lplane + dy * LR;
#pragma unroll
    for (int c = 0; c < NFULL; ++c) {
      GLDS(row + 4 * (64 * c + lane), lrow + 64 * c);
    }
    if (REM && lane < REM) {  // exec!=0 always -> vmcnt still +1 per wave
      GLDS(row + 4 * (64 * NFULL + lane), lrow + 64 * NFULL);
    }
  }
}

template <int K, int WK, int HK>
__device__ __forceinline__ void gather_k(const float* lplane, int bx0, int by0,
                                         float xg, float yg, float* r) {
  float cth, sth;
  ktrig<K>(cth, sth);
  float xs = cth * xg + sth * yg + 63.5f;  // no fma (contract off)
  float ys = (-sth) * xg + cth * yg + 63.5f;
  int xi = (int)rintf(xs);  // round-half-even == jnp.round
  int yi = (int)rintf(ys);
  bool valid = ((unsigned)xi < (unsigned)WW) & ((unsigned)yi < (unsigned)HH);
  // valid => xi-bx0 in [0,WK) proven; clamp only guards invalid lanes' LDS
  // addressing.
  int dxr = min(max(xi - bx0, 0), WK - 1);
  int dyr = min(max(yi - by0, 0), HK - 1);
  const float2* lp = (const float2*)(lplane + dyr * (WK * GG) + dxr * GG);
  float2 v01 = lp[0];
  float2 v23 = lp[1];
  float2 v45 = lp[2];
  r[0] = fmaxf(r[0], valid ? v01.x : 0.0f);  // zero fill joins the max
  r[1] = fmaxf(r[1], valid ? v01.y : 0.0f);
  r[2] = fmaxf(r[2], valid ? v23.x : 0.0f);
  r[3] = fmaxf(r[3], valid ? v23.y : 0.0f);
  r[4] = fmaxf(r[4], valid ? v45.x : 0.0f);
  r[5] = fmaxf(r[5], valid ? v45.y : 0.0f);
}

__global__ __launch_bounds__(512, 4) void glp_rotation_pool_kernel(
    const float* __restrict__ img, float* __restrict__ out) {
  __shared__ __align__(16) float buf0[6480];  // max(32*16, 36*30) * 6
  __shared__ __align__(16) float buf1[6936];  // max(35*24, 34*34) * 6

  // 4096 blocks = 128 slices x 32 tiles (4x in x, 8 in y); xcd = blk&7
  // round-robin heuristic: each XCD works 16 slices, tiles of one slice
  // together in its L2.
  int blk = blockIdx.x;
  int xcd = blk & 7;
  int i = blk >> 3;                // 0..511
  int bc = (xcd << 4) | (i >> 5);  // slice 0..127
  int tile = i & 31;
  int ty = (tile >> 2) << 4;  // 0..112 step 16
  int tx = (tile & 3) << 5;   // 0,32,64,96

  int tid = threadIdx.x;  // 0..511
  int px = tid & 31;
  int py = tid >> 5;  // 0..15
  int wave = tid >> 6;
  int lane = tid & 63;

  const float* sbase = img + (size_t)bc * (HH * WW * AA);

  float xg = (float)(tx + px) - 63.5f;
  float yg = (float)(ty + py) - 63.5f;
  float xga = (float)tx - 63.5f, xgb = (float)(tx + TW - 1) - 63.5f;
  float yga = (float)ty - 63.5f, ygb = (float)(ty + TH - 1) - 63.5f;

  int bx0_0, by0_0, bx0_1, by0_1, bx0_2, by0_2, bx0_3, by0_3;
  window_k<0, 32, 16>(xga, xgb, yga, ygb, bx0_0, by0_0);
  window_k<1, 35, 24>(xga, xgb, yga, ygb, bx0_1, by0_1);
  window_k<2, 36, 30>(xga, xgb, yga, ygb, bx0_2, by0_2);
  window_k<3, 34, 34>(xga, xgb, yga, ygb, bx0_3, by0_3);

  float r[6] = {-INFINITY, -INFINITY, -INFINITY,
                -INFINITY, -INFINITY, -INFINITY};

  // Pipeline: per-wave gl_lds issue counts are {6,12,16,20} for k={0,1,2,3}.
  // Counted vmcnt leaves the next k's loads in flight (in-order completion).
  stage_k<0, 32, 16>(sbase, buf0, bx0_0, by0_0, wave, lane);  // +6
  stage_k<1, 35, 24>(sbase, buf1, bx0_1, by0_1, wave, lane);  // +12 (out 18)
  asm volatile("s_waitcnt vmcnt(12)" ::: "memory");           // k0 landed
  __builtin_amdgcn_sched_barrier(0);
  __builtin_amdgcn_s_barrier();
  __builtin_amdgcn_sched_barrier(0);
  gather_k<0, 32, 16>(buf0, bx0_0, by0_0, xg, yg, r);
  __builtin_amdgcn_s_barrier();  // all waves done reading buf0
  __builtin_amdgcn_sched_barrier(0);
  stage_k<2, 36, 30>(sbase, buf0, bx0_2, by0_2, wave, lane);  // +16 (out 28)
  asm volatile("s_waitcnt vmcnt(16)" ::: "memory");           // k1 landed
  __builtin_amdgcn_sched_barrier(0);
  __builtin_amdgcn_s_barrier();
  __builtin_amdgcn_sched_barrier(0);
  gather_k<1, 35, 24>(buf1, bx0_1, by0_1, xg, yg, r);
  __builtin_amdgcn_s_barrier();  // all waves done reading buf1
  __builtin_amdgcn_sched_barrier(0);
  stage_k<3, 34, 34>(sbase, buf1, bx0_3, by0_3, wave, lane);  // +20 (out 36)
  asm volatile("s_waitcnt vmcnt(20)" ::: "memory");           // k2 landed
  __builtin_amdgcn_sched_barrier(0);
  __builtin_amdgcn_s_barrier();
  __builtin_amdgcn_sched_barrier(0);
  gather_k<2, 36, 30>(buf0, bx0_2, by0_2, xg, yg, r);
  asm volatile("s_waitcnt vmcnt(0)" ::: "memory");  // k3 landed
  __builtin_amdgcn_sched_barrier(0);
  __builtin_amdgcn_s_barrier();
  __builtin_amdgcn_sched_barrier(0);
  gather_k<3, 34, 34>(buf1, bx0_3, by0_3, xg, yg, r);

  // out float index = ((bc*H*W + y*W + x)*G); 24B per pixel, 8B-aligned.
  size_t opix =
      ((size_t)bc * (HH * WW) + (size_t)(ty + py) * WW + (tx + px)) * GG;
  float2* op = (float2*)&out[opix];
  op[0] = make_float2(r[0], r[1]);
  op[1] = make_float2(r[2], r[3]);
  op[2] = make_float2(r[4], r[5]);
}

extern "C" void kernel_launch(void* const* d_in, const int* in_sizes, int n_in,
                              void* d_out, int out_size, void* d_ws,
                              size_t ws_size, hipStream_t stream) {
  const float* img = (const float*)d_in[0];
  float* out = (float*)d_out;
  // 128 slices * 32 tiles = 4096 blocks of 512 threads
  dim3 grid(128 * 32);
  dim3 block(512);
  glp_rotation_pool_kernel<<<grid, block, 0, stream>>>(img, out);
}